// Round 1
// baseline (196.613 us; speedup 1.0000x reference)
//
#include <hip/hip_runtime.h>
#include <hip/hip_bf16.h>
#include <stdint.h>

#define DIM 128
#define ODIM 64
#define BM 128
#define BN 64
#define NSPLIT 32

typedef __attribute__((ext_vector_type(8))) __bf16 bf16x8;
typedef __attribute__((ext_vector_type(2))) __bf16 bf16x2;
typedef __attribute__((ext_vector_type(4))) float f32x4;

#define MFMA16(a, b, c) __builtin_amdgcn_mfma_f32_16x16x32_bf16((a), (b), (c), 0, 0, 0)

__device__ __forceinline__ void async_copy16(const void* g, void* l) {
  __builtin_amdgcn_global_load_lds((const __attribute__((address_space(1))) void*)g,
                                   (__attribute__((address_space(3))) void*)l, 16, 0, 0);
}
__device__ __forceinline__ void async_copy4(const void* g, void* l) {
  __builtin_amdgcn_global_load_lds((const __attribute__((address_space(1))) void*)g,
                                   (__attribute__((address_space(3))) void*)l, 4, 0, 0);
}

// ---- Prepass: fp32 rows -> bf16 rows + per-row sum of squares (one wave per row).
// Rows in [nValid, nPad) are zero-filled and get sq = padSq (1e30 => k underflows to 0).
__global__ void rows_to_bf16_sq(const float* __restrict__ src, __bf16* __restrict__ dst,
                                float* __restrict__ sq, int nValid, int nPad, float padSq) {
  int row = blockIdx.x * 4 + (threadIdx.x >> 6);
  int lane = threadIdx.x & 63;
  if (row >= nPad) return;
  float2 v = make_float2(0.0f, 0.0f);
  if (row < nValid) v = ((const float2*)src)[(size_t)row * 64 + lane];
  bf16x2 p;
  p.x = (__bf16)v.x;
  p.y = (__bf16)v.y;
  *(bf16x2*)&dst[(size_t)row * DIM + lane * 2] = p;
  float ss = v.x * v.x + v.y * v.y;
  #pragma unroll
  for (int off = 32; off > 0; off >>= 1) ss += __shfl_down(ss, off);
  if (lane == 0) sq[row] = (row < nValid) ? ss : padSq;
}

// ---- Prepass: weights [N][64] fp32 -> Wt [64][Npad] bf16 (transpose via LDS tile).
__global__ void transpose_weights(const float* __restrict__ W, __bf16* __restrict__ Wt,
                                  int N, int Npad) {
  __shared__ float tile[64][65];
  int j0 = (int)blockIdx.x * 64;
  int t = threadIdx.x;
  int jr = t >> 2;
  int cg = (t & 3) * 16;
  int j = j0 + jr;
  if (j < N) {
    const float4* src = (const float4*)(W + (size_t)j * ODIM);
    #pragma unroll
    for (int q = 0; q < 4; ++q) {
      float4 u = src[(cg >> 2) + q];
      tile[jr][cg + q * 4 + 0] = u.x;
      tile[jr][cg + q * 4 + 1] = u.y;
      tile[jr][cg + q * 4 + 2] = u.z;
      tile[jr][cg + q * 4 + 3] = u.w;
    }
  } else {
    #pragma unroll
    for (int q = 0; q < 16; ++q) tile[jr][cg + q] = 0.0f;
  }
  __syncthreads();
  int v = t >> 2;
  int jc = (t & 3) * 16;
  __bf16 ob[16];
  #pragma unroll
  for (int q = 0; q < 16; ++q) ob[q] = (__bf16)tile[jc + q][v];
  __bf16* dst = Wt + (size_t)v * Npad + j0 + jc;
  *(bf16x8*)dst = *(bf16x8*)&ob[0];
  *(bf16x8*)(dst + 8) = *(bf16x8*)&ob[8];
}

// ---- Main fused kernel: per block, M-tile of 128 feature rows x one N-split of
// train chunks (BN=64). S = F·T^T (MFMA, F-frags in registers), elementwise
// dist->exp, P round-trip through LDS, O += P·W (MFMA). Partials per split.
template <bool ATOMIC>
__global__ __launch_bounds__(256) void rbf_main(
    const __bf16* __restrict__ Fb, const __bf16* __restrict__ Tb,
    const __bf16* __restrict__ Wt, const float* __restrict__ t2g,
    const float* __restrict__ x2g, float* __restrict__ outOrPart,
    int nRows, int Npad, int nChunks) {
  __shared__ __bf16 sT[BN * DIM];        // 16 KB, XOR-swizzled 16B granules
  __shared__ __bf16 sW[ODIM * BN];       // 8 KB, XOR-swizzled 16B granules
  __shared__ __bf16 sP[BM * (BN + 8)];   // 18 KB, +8 pad (row stride 144B = 9*16)
  __shared__ float st2[BN];

  const int tid = threadIdx.x;
  const int wave = tid >> 6;
  const int lane = tid & 63;
  const int l16 = lane & 15;
  const int g4 = lane >> 4;

  const int mb = (int)blockIdx.x >> 5;           // 0..15
  const int ns = (int)blockIdx.x & (NSPLIT - 1); // 0..31

  const float inv2co = (float)(1.0 / (2.0 * 10.077141124806595));

  // F fragments live in registers for the whole block (rows wave*32 + {0,16} + l16).
  bf16x8 aF[2][4];
  #pragma unroll
  for (int mi = 0; mi < 2; ++mi)
    #pragma unroll
    for (int ko = 0; ko < 4; ++ko)
      aF[mi][ko] = *(const bf16x8*)(Fb + ((size_t)(mb * BM + wave * 32 + mi * 16 + l16)) * DIM +
                                    ko * 32 + g4 * 8);

  float x2r[8];
  #pragma unroll
  for (int mi = 0; mi < 2; ++mi)
    #pragma unroll
    for (int r = 0; r < 4; ++r)
      x2r[mi * 4 + r] = x2g[mb * BM + wave * 32 + mi * 16 + g4 * 4 + r];

  f32x4 zero4 = {0.0f, 0.0f, 0.0f, 0.0f};
  f32x4 oacc[2][4];
  #pragma unroll
  for (int mi = 0; mi < 2; ++mi)
    #pragma unroll
    for (int vi = 0; vi < 4; ++vi) oacc[mi][vi] = zero4;

  for (int c = ns; c < nChunks; c += NSPLIT) {
    const int n0 = c * BN;

    // Stage T chunk [64][128] bf16. LDS granule (row,g) holds global granule g^(row&15).
    {
      const char* gT = (const char*)Tb + (size_t)n0 * 256;
      #pragma unroll
      for (int i = 0; i < 4; ++i) {
        int off = i * 4096 + wave * 1024;            // wave-uniform LDS base
        int loff = off + lane * 16;
        int row = loff >> 8;
        int gran = (loff >> 4) & 15;
        async_copy16(gT + row * 256 + ((gran ^ (row & 15)) << 4), (char*)sT + off);
      }
    }
    // Stage W chunk: sW[v][0..63] = Wt[v][n0..n0+63]; granule g holds global g^(v&7).
    {
      #pragma unroll
      for (int i = 0; i < 2; ++i) {
        int off = i * 4096 + wave * 1024;
        int loff = off + lane * 16;
        int v = loff >> 7;
        int gran = (loff >> 4) & 7;
        const char* gW = (const char*)Wt + ((size_t)v * Npad + n0) * 2 + ((gran ^ (v & 7)) << 4);
        async_copy16(gW, (char*)sW + off);
      }
    }
    if (wave == 0) async_copy4((const char*)(t2g + n0) + lane * 4, (char*)st2);
    __syncthreads();

    // S = F · T^T  (strip: 32 rows x 64 train-cols per wave)
    f32x4 sacc[2][4];
    #pragma unroll
    for (int mi = 0; mi < 2; ++mi)
      #pragma unroll
      for (int ni = 0; ni < 4; ++ni) sacc[mi][ni] = zero4;

    #pragma unroll
    for (int ko = 0; ko < 4; ++ko) {
      bf16x8 b[4];
      #pragma unroll
      for (int ni = 0; ni < 4; ++ni) {
        int nn = ni * 16 + l16;
        int slot = (ko * 4 + g4) ^ l16;
        b[ni] = *(const bf16x8*)((const char*)sT + nn * 256 + (slot << 4));
      }
      #pragma unroll
      for (int mi = 0; mi < 2; ++mi)
        #pragma unroll
        for (int ni = 0; ni < 4; ++ni)
          sacc[mi][ni] = MFMA16(aF[mi][ko], b[ni], sacc[mi][ni]);
    }

    float t2v[4];
    #pragma unroll
    for (int ni = 0; ni < 4; ++ni) t2v[ni] = st2[ni * 16 + l16];

    // elementwise: d2 = x2 + t2 - 2S; k = exp(-sqrt(d2)*inv2co); write P (bf16) to LDS
    #pragma unroll
    for (int mi = 0; mi < 2; ++mi)
      #pragma unroll
      for (int ni = 0; ni < 4; ++ni)
        #pragma unroll
        for (int r = 0; r < 4; ++r) {
          float s = sacc[mi][ni][r];
          float d2 = x2r[mi * 4 + r] + t2v[ni] - 2.0f * s;
          float dist = sqrtf(fmaxf(d2, 0.0f));
          float kv = __expf(-inv2co * dist);
          int row = wave * 32 + mi * 16 + g4 * 4 + r;
          int col = ni * 16 + l16;
          sP[row * (BN + 8) + col] = (__bf16)kv;
        }
    __syncthreads();

    // O += P · W   (A-frags from sP, B-frags from swizzled sW)
    #pragma unroll
    for (int ko = 0; ko < 2; ++ko) {
      int kb = ko * 32 + g4 * 8;
      bf16x8 p0 = *(const bf16x8*)&sP[(wave * 32 + l16) * (BN + 8) + kb];
      bf16x8 p1 = *(const bf16x8*)&sP[(wave * 32 + 16 + l16) * (BN + 8) + kb];
      bf16x8 w[4];
      #pragma unroll
      for (int vi = 0; vi < 4; ++vi) {
        int v = vi * 16 + l16;
        int slot = (ko * 4 + g4) ^ (l16 & 7);
        w[vi] = *(const bf16x8*)((const char*)sW + v * 128 + (slot << 4));
      }
      #pragma unroll
      for (int vi = 0; vi < 4; ++vi) {
        oacc[0][vi] = MFMA16(p0, w[vi], oacc[0][vi]);
        oacc[1][vi] = MFMA16(p1, w[vi], oacc[1][vi]);
      }
    }
    __syncthreads();
  }

  if (ATOMIC) {
    float* out = outOrPart;
    #pragma unroll
    for (int mi = 0; mi < 2; ++mi)
      #pragma unroll
      for (int vi = 0; vi < 4; ++vi)
        #pragma unroll
        for (int r = 0; r < 4; ++r) {
          int row = mb * BM + wave * 32 + mi * 16 + g4 * 4 + r;
          int col = vi * 16 + l16;
          atomicAdd(&out[(size_t)row * ODIM + col], oacc[mi][vi][r]);
        }
  } else {
    float* dst = outOrPart + (size_t)ns * (size_t)nRows * ODIM;
    #pragma unroll
    for (int mi = 0; mi < 2; ++mi)
      #pragma unroll
      for (int vi = 0; vi < 4; ++vi)
        #pragma unroll
        for (int r = 0; r < 4; ++r) {
          int row = mb * BM + wave * 32 + mi * 16 + g4 * 4 + r;
          int col = vi * 16 + l16;
          dst[(size_t)row * ODIM + col] = oacc[mi][vi][r];
        }
  }
}

__global__ void reduce_parts(const float* __restrict__ part, float* __restrict__ out, int total) {
  int i = (int)blockIdx.x * blockDim.x + threadIdx.x;
  if (i >= total) return;
  float s = 0.0f;
  #pragma unroll
  for (int sp = 0; sp < NSPLIT; ++sp) s += part[(size_t)sp * total + i];
  out[i] = s;
}

extern "C" void kernel_launch(void* const* d_in, const int* in_sizes, int n_in,
                              void* d_out, int out_size, void* d_ws, size_t ws_size,
                              hipStream_t stream) {
  (void)n_in;
  const float* features = (const float*)d_in[0];
  const float* train = (const float*)d_in[1];
  const float* weights = (const float*)d_in[2];
  float* out = (float*)d_out;

  const int n = in_sizes[0] / DIM;              // 2048
  const int N = in_sizes[1] / DIM;              // 50000
  const int Npad = ((N + 63) / 64) * 64;        // 50048
  const int nChunks = Npad / 64;                // 782

  size_t off = 0;
  auto alloc = [&](size_t bytes) {
    size_t o = off;
    off = (off + bytes + 255) & ~(size_t)255;
    return o;
  };
  size_t oT = alloc((size_t)Npad * DIM * 2);
  size_t oW = alloc((size_t)ODIM * Npad * 2);
  size_t oF = alloc((size_t)n * DIM * 2);
  size_t ot2 = alloc((size_t)Npad * 4);
  size_t ox2 = alloc((size_t)n * 4);
  size_t needNoPart = off;
  size_t oPart = alloc((size_t)NSPLIT * n * ODIM * 4);
  size_t needFull = off;

  char* ws = (char*)d_ws;
  __bf16* Tb = (__bf16*)(ws + oT);
  __bf16* Wt = (__bf16*)(ws + oW);
  __bf16* Fb = (__bf16*)(ws + oF);
  float* t2 = (float*)(ws + ot2);
  float* x2 = (float*)(ws + ox2);

  rows_to_bf16_sq<<<Npad / 4, 256, 0, stream>>>(train, Tb, t2, N, Npad, 1e30f);
  rows_to_bf16_sq<<<n / 4, 256, 0, stream>>>(features, Fb, x2, n, n, 0.0f);
  transpose_weights<<<Npad / 64, 256, 0, stream>>>(weights, Wt, N, Npad);

  const int mBlocks = n / BM;                    // 16
  dim3 grid(mBlocks * NSPLIT);                   // 512 blocks = 2/CU

  if (ws_size >= needFull) {
    float* part = (float*)(ws + oPart);
    rbf_main<false><<<grid, 256, 0, stream>>>(Fb, Tb, Wt, t2, x2, part, n, Npad, nChunks);
    int total = n * ODIM;
    reduce_parts<<<(total + 255) / 256, 256, 0, stream>>>(part, out, total);
  } else {
    (void)needNoPart;
    hipMemsetAsync(d_out, 0, (size_t)out_size * sizeof(float), stream);
    rbf_main<true><<<grid, 256, 0, stream>>>(Fb, Tb, Wt, t2, x2, out, n, Npad, nChunks);
  }
}

// Round 2
// 146.038 us; speedup vs baseline: 1.3463x; 1.3463x over previous
//
#include <hip/hip_runtime.h>
#include <hip/hip_bf16.h>
#include <stdint.h>

#define DIM 128
#define ODIM 64
#define BM 128
#define BN 64
#define NSPLIT 48
#define SPROW 72   // sP row length in bf16: 64 + 8 pad -> 144 B = 9*16, b128-aligned

typedef __attribute__((ext_vector_type(8))) __bf16 bf16x8;
typedef __attribute__((ext_vector_type(2))) __bf16 bf16x2;
typedef __attribute__((ext_vector_type(4))) float f32x4;

#define MFMA16(a, b, c) __builtin_amdgcn_mfma_f32_16x16x32_bf16((a), (b), (c), 0, 0, 0)

// c = log2(e) / (2*RBF_CO);  k = exp(-dist/(2*co)) = 2^(-c*dist) = 2^(-sqrt(c^2*d2))
#define RBFD 10.077141124806595
#define LOG2E 1.4426950408889634
#define C2D ((LOG2E / (2.0 * RBFD)) * (LOG2E / (2.0 * RBFD)))

__device__ __forceinline__ void async_copy16(const void* g, void* l) {
  __builtin_amdgcn_global_load_lds((const __attribute__((address_space(1))) void*)g,
                                   (__attribute__((address_space(3))) void*)l, 16, 0, 0);
}
__device__ __forceinline__ void async_copy4(const void* g, void* l) {
  __builtin_amdgcn_global_load_lds((const __attribute__((address_space(1))) void*)g,
                                   (__attribute__((address_space(3))) void*)l, 4, 0, 0);
}

// round-half-up bf16 pack: lo=a, hi=b  (values are finite positive; +0x8000 then take hi16)
__device__ __forceinline__ uint32_t pack_bf16(float a, float b) {
  uint32_t ua = __builtin_bit_cast(uint32_t, a) + 0x8000u;
  uint32_t ub = __builtin_bit_cast(uint32_t, b) + 0x8000u;
  return __builtin_amdgcn_perm(ub, ua, 0x07060302u);  // bytes: [ua.b2, ua.b3, ub.b2, ub.b3] -> lo16=a.hi, hi16=b.hi
}

// ---- Prepass: fp32 rows -> bf16 rows + scaled per-row sum of squares (one wave per row).
// Handles both train (blocks [0, trainBlocks)) and features (rest) in one launch.
__global__ void prep_rows(const float* __restrict__ train, __bf16* __restrict__ Tb,
                          float* __restrict__ t2, const float* __restrict__ feat,
                          __bf16* __restrict__ Fb, float* __restrict__ x2,
                          int Ntrain, int NpadTrain, int nFeat, int trainBlocks, float scale) {
  int b = blockIdx.x;
  const float* src;
  __bf16* dst;
  float* sq;
  int nValid, nPad, row0;
  float padv;
  if (b < trainBlocks) {
    src = train; dst = Tb; sq = t2; nValid = Ntrain; nPad = NpadTrain; row0 = b * 4; padv = 1e30f;
  } else {
    src = feat; dst = Fb; sq = x2; nValid = nFeat; nPad = nFeat; row0 = (b - trainBlocks) * 4; padv = 0.0f;
  }
  int row = row0 + (threadIdx.x >> 6);
  int lane = threadIdx.x & 63;
  if (row >= nPad) return;
  float2 v = make_float2(0.0f, 0.0f);
  if (row < nValid) v = ((const float2*)src)[(size_t)row * 64 + lane];
  bf16x2 p;
  p.x = (__bf16)v.x;
  p.y = (__bf16)v.y;
  *(bf16x2*)&dst[(size_t)row * DIM + lane * 2] = p;
  float ss = v.x * v.x + v.y * v.y;
  #pragma unroll
  for (int off = 32; off > 0; off >>= 1) ss += __shfl_down(ss, off);
  if (lane == 0) sq[row] = (row < nValid) ? ss * scale : padv;
}

// ---- Prepass: weights [N][64] fp32 -> Wt [64][Npad] bf16 (transpose via LDS tile).
__global__ void transpose_weights(const float* __restrict__ W, __bf16* __restrict__ Wt,
                                  int N, int Npad) {
  __shared__ float tile[64][65];
  int j0 = (int)blockIdx.x * 64;
  int t = threadIdx.x;
  int jr = t >> 2;
  int cg = (t & 3) * 16;
  int j = j0 + jr;
  if (j < N) {
    const float4* src = (const float4*)(W + (size_t)j * ODIM);
    #pragma unroll
    for (int q = 0; q < 4; ++q) {
      float4 u = src[(cg >> 2) + q];
      tile[jr][cg + q * 4 + 0] = u.x;
      tile[jr][cg + q * 4 + 1] = u.y;
      tile[jr][cg + q * 4 + 2] = u.z;
      tile[jr][cg + q * 4 + 3] = u.w;
    }
  } else {
    #pragma unroll
    for (int q = 0; q < 16; ++q) tile[jr][cg + q] = 0.0f;
  }
  __syncthreads();
  int v = t >> 2;
  int jc = (t & 3) * 16;
  __bf16 ob[16];
  #pragma unroll
  for (int q = 0; q < 16; ++q) ob[q] = (__bf16)tile[jc + q][v];
  __bf16* dst = Wt + (size_t)v * Npad + j0 + jc;
  *(bf16x8*)dst = *(bf16x8*)&ob[0];
  *(bf16x8*)(dst + 8) = *(bf16x8*)&ob[8];
}

// ---- Main fused kernel (S^T formulation).
// Per block: 128 feature rows x one N-split of 64-train-col chunks.
// S^T = T·F^T (A = T-frags from sT, B = F-frags in registers) -> C-layout has
// feat on lane&15 and 4 consecutive train-k per reg quad -> P written to LDS as
// packed b64, read back as aligned b128 A-frags for O += P·W. Wave-private P strip.
template <bool ATOMIC>
__global__ __launch_bounds__(256, 3) void rbf_main(
    const __bf16* __restrict__ Fb, const __bf16* __restrict__ Tb,
    const __bf16* __restrict__ Wt, const float* __restrict__ t2g,
    const float* __restrict__ x2g, float* __restrict__ outOrPart,
    int nRows, int Npad, int nChunks) {
  __shared__ __bf16 sT[BN * DIM];        // 16 KB, XOR-swizzled 16B granules
  __shared__ __bf16 sW[ODIM * BN];       // 8 KB, XOR-swizzled 16B granules
  __shared__ __bf16 sP[BM * SPROW];      // 18 KB, wave-private 32-row strips
  __shared__ float st2[BN];              // scaled t2 for this chunk

  const int tid = threadIdx.x;
  const int wave = tid >> 6;
  const int lane = tid & 63;
  const int l16 = lane & 15;
  const int g4 = lane >> 4;

  const int ns = (int)blockIdx.x;        // 0..NSPLIT-1
  const int mb = (int)blockIdx.y;        // 0..15

  constexpr float KNEG2 = (float)(-2.0 * C2D);

  // F fragments (chunk-invariant): rows mb*128 + wave*32 + nf*16 + l16, 8 k each.
  bf16x8 bF[2][4];
  #pragma unroll
  for (int nf = 0; nf < 2; ++nf)
    #pragma unroll
    for (int ko = 0; ko < 4; ++ko)
      bF[nf][ko] = *(const bf16x8*)(Fb + ((size_t)(mb * BM + wave * 32 + nf * 16 + l16)) * DIM +
                                    ko * 32 + g4 * 8);

  float x2v[2];
  #pragma unroll
  for (int nf = 0; nf < 2; ++nf)
    x2v[nf] = x2g[mb * BM + wave * 32 + nf * 16 + l16];  // pre-scaled by c^2

  f32x4 zero4 = {0.0f, 0.0f, 0.0f, 0.0f};
  f32x4 oacc[2][4];
  #pragma unroll
  for (int mo = 0; mo < 2; ++mo)
    #pragma unroll
    for (int vi = 0; vi < 4; ++vi) oacc[mo][vi] = zero4;

  for (int c = ns; c < nChunks; c += NSPLIT) {
    const int n0 = c * BN;

    // Stage T chunk [64][128] bf16. LDS granule (row,g) holds global granule g^(row&15).
    {
      const char* gT = (const char*)Tb + (size_t)n0 * 256;
      #pragma unroll
      for (int i = 0; i < 4; ++i) {
        int off = i * 4096 + wave * 1024;  // wave-uniform LDS base
        int loff = off + lane * 16;
        int row = loff >> 8;
        int gran = (loff >> 4) & 15;
        async_copy16(gT + row * 256 + ((gran ^ (row & 15)) << 4), (char*)sT + off);
      }
    }
    // Stage W chunk: sW[v][0..63] = Wt[v][n0..n0+63]; granule g holds global g^(v&7).
    {
      #pragma unroll
      for (int i = 0; i < 2; ++i) {
        int off = i * 4096 + wave * 1024;
        int loff = off + lane * 16;
        int v = loff >> 7;
        int gran = (loff >> 4) & 7;
        const char* gW = (const char*)Wt + ((size_t)v * Npad + n0) * 2 + ((gran ^ (v & 7)) << 4);
        async_copy16(gW, (char*)sW + off);
      }
    }
    if (wave == 0) async_copy4((const char*)(t2g + n0) + lane * 4, (char*)st2);
    __syncthreads();

    // S^T = T · F^T : tiles m = train (4), n = feat (2 per wave)
    f32x4 sacc[4][2];
    #pragma unroll
    for (int mt = 0; mt < 4; ++mt)
      #pragma unroll
      for (int nf = 0; nf < 2; ++nf) sacc[mt][nf] = zero4;

    #pragma unroll
    for (int ko = 0; ko < 4; ++ko) {
      bf16x8 a[4];
      #pragma unroll
      for (int mt = 0; mt < 4; ++mt) {
        int row = mt * 16 + l16;
        int slot = (ko * 4 + g4) ^ l16;
        a[mt] = *(const bf16x8*)((const char*)sT + row * 256 + (slot << 4));
      }
      #pragma unroll
      for (int mt = 0; mt < 4; ++mt)
        #pragma unroll
        for (int nf = 0; nf < 2; ++nf)
          sacc[mt][nf] = MFMA16(a[mt], bF[nf][ko], sacc[mt][nf]);
    }

    // elementwise: d2' = x2' + t2' - 2c^2*s ; k = 2^(-sqrt(d2')) ; pack 4 bf16 -> b64 write
    #pragma unroll
    for (int mt = 0; mt < 4; ++mt) {
      f32x4 t2v = *(const f32x4*)&st2[mt * 16 + g4 * 4];
      #pragma unroll
      for (int nf = 0; nf < 2; ++nf) {
        f32x4 s = sacc[mt][nf];
        float kv[4];
        #pragma unroll
        for (int r = 0; r < 4; ++r) {
          float d2 = __builtin_fmaf(KNEG2, s[r], t2v[r] + x2v[nf]);
          d2 = fmaxf(d2, 0.0f);
          kv[r] = __builtin_amdgcn_exp2f(-__builtin_amdgcn_sqrtf(d2));
        }
        uint32_t lo = pack_bf16(kv[0], kv[1]);
        uint32_t hi = pack_bf16(kv[2], kv[3]);
        uint2* dst = (uint2*)&sP[(wave * 32 + nf * 16 + l16) * SPROW + mt * 16 + g4 * 4];
        *dst = make_uint2(lo, hi);
      }
    }
    // NOTE: no barrier — each wave's sP strip is written and read only by itself
    // (compiler inserts lgkmcnt waits for the LDS dependency).

    // O += P · W
    #pragma unroll
    for (int ko2 = 0; ko2 < 2; ++ko2) {
      bf16x8 p[2];
      #pragma unroll
      for (int mo = 0; mo < 2; ++mo)
        p[mo] = *(const bf16x8*)&sP[(wave * 32 + mo * 16 + l16) * SPROW + ko2 * 32 + g4 * 8];
      bf16x8 w[4];
      #pragma unroll
      for (int vi = 0; vi < 4; ++vi) {
        int v = vi * 16 + l16;
        int slot = (ko2 * 4 + g4) ^ (l16 & 7);
        w[vi] = *(const bf16x8*)((const char*)sW + v * 128 + (slot << 4));
      }
      #pragma unroll
      for (int mo = 0; mo < 2; ++mo)
        #pragma unroll
        for (int vi = 0; vi < 4; ++vi)
          oacc[mo][vi] = MFMA16(p[mo], w[vi], oacc[mo][vi]);
    }
    __syncthreads();  // protect sT/sW from next chunk's staging
  }

  if (ATOMIC) {
    float* out = outOrPart;
    #pragma unroll
    for (int mo = 0; mo < 2; ++mo)
      #pragma unroll
      for (int vi = 0; vi < 4; ++vi)
        #pragma unroll
        for (int r = 0; r < 4; ++r) {
          int row = mb * BM + wave * 32 + mo * 16 + g4 * 4 + r;
          int col = vi * 16 + l16;
          atomicAdd(&out[(size_t)row * ODIM + col], oacc[mo][vi][r]);
        }
  } else {
    float* dst = outOrPart + (size_t)ns * (size_t)nRows * ODIM;
    #pragma unroll
    for (int mo = 0; mo < 2; ++mo)
      #pragma unroll
      for (int vi = 0; vi < 4; ++vi)
        #pragma unroll
        for (int r = 0; r < 4; ++r) {
          int row = mb * BM + wave * 32 + mo * 16 + g4 * 4 + r;
          int col = vi * 16 + l16;
          dst[(size_t)row * ODIM + col] = oacc[mo][vi][r];
        }
  }
}

__global__ void reduce_parts(const float4* __restrict__ part, float4* __restrict__ out,
                             int total4) {
  int i = (int)blockIdx.x * blockDim.x + threadIdx.x;
  if (i >= total4) return;
  float4 s = make_float4(0.0f, 0.0f, 0.0f, 0.0f);
  #pragma unroll
  for (int sp = 0; sp < NSPLIT; ++sp) {
    float4 v = part[(size_t)sp * total4 + i];
    s.x += v.x; s.y += v.y; s.z += v.z; s.w += v.w;
  }
  out[i] = s;
}

extern "C" void kernel_launch(void* const* d_in, const int* in_sizes, int n_in,
                              void* d_out, int out_size, void* d_ws, size_t ws_size,
                              hipStream_t stream) {
  (void)n_in;
  const float* features = (const float*)d_in[0];
  const float* train = (const float*)d_in[1];
  const float* weights = (const float*)d_in[2];
  float* out = (float*)d_out;

  const int n = in_sizes[0] / DIM;              // 2048
  const int N = in_sizes[1] / DIM;              // 50000
  const int Npad = ((N + 63) / 64) * 64;        // 50048
  const int nChunks = Npad / 64;                // 782

  size_t off = 0;
  auto alloc = [&](size_t bytes) {
    size_t o = off;
    off = (off + bytes + 255) & ~(size_t)255;
    return o;
  };
  size_t oT = alloc((size_t)Npad * DIM * 2);
  size_t oW = alloc((size_t)ODIM * Npad * 2);
  size_t oF = alloc((size_t)n * DIM * 2);
  size_t ot2 = alloc((size_t)Npad * 4);
  size_t ox2 = alloc((size_t)n * 4);
  size_t oPart = alloc((size_t)NSPLIT * n * ODIM * 4);
  size_t needFull = off;

  char* ws = (char*)d_ws;
  __bf16* Tb = (__bf16*)(ws + oT);
  __bf16* Wt = (__bf16*)(ws + oW);
  __bf16* Fb = (__bf16*)(ws + oF);
  float* t2 = (float*)(ws + ot2);
  float* x2 = (float*)(ws + ox2);

  const float scale = (float)C2D;
  const int trainBlocks = Npad / 4;
  prep_rows<<<trainBlocks + n / 4, 256, 0, stream>>>(train, Tb, t2, features, Fb, x2,
                                                     N, Npad, n, trainBlocks, scale);
  transpose_weights<<<Npad / 64, 256, 0, stream>>>(weights, Wt, N, Npad);

  const int mBlocks = n / BM;                    // 16
  dim3 grid(NSPLIT, mBlocks);                    // 768 blocks = 3/CU

  if (ws_size >= needFull) {
    float* part = (float*)(ws + oPart);
    rbf_main<false><<<grid, 256, 0, stream>>>(Fb, Tb, Wt, t2, x2, part, n, Npad, nChunks);
    int total4 = n * ODIM / 4;
    reduce_parts<<<(total4 + 255) / 256, 256, 0, stream>>>((const float4*)part, (float4*)out,
                                                           total4);
  } else {
    hipMemsetAsync(d_out, 0, (size_t)out_size * sizeof(float), stream);
    rbf_main<true><<<grid, 256, 0, stream>>>(Fb, Tb, Wt, t2, x2, out, n, Npad, nChunks);
  }
}